// Round 23
// baseline (208.294 us; speedup 1.0000x reference)
//
#include <hip/hip_runtime.h>
#include <hip/hip_bf16.h>

#define T_SEQ 2048
#define NEMBD 512
#define NHEAD 4
#define HDIM  128
#define BATCH 8
#define MROWS (BATCH * T_SEQ)          // 16384
// 1/sqrt(128) * log2(e): QK^T scores land in log2 domain -> exp2 in softmax
#define QSCALE 0.12751744534f

typedef __attribute__((ext_vector_type(8))) short short8;
typedef __attribute__((ext_vector_type(4))) short short4v;
typedef __attribute__((ext_vector_type(4))) float f32x4;

static __device__ __forceinline__ float bf2f(unsigned short h) {
  return __uint_as_float(((unsigned int)h) << 16);
}
static __device__ __forceinline__ short f2bs(float f) {   // RNE f32->bf16 bits
  unsigned int u = __float_as_uint(f);
  unsigned int r = (u + 0x7FFFu + ((u >> 16) & 1u)) >> 16;
  return (short)r;
}
// pack two floats -> u32 of 2 bf16 (v_cvt_pk_bf16_f32)
static __device__ __forceinline__ unsigned int pk2(float a, float b) {
  __hip_bfloat162 h = __float22bfloat162_rn(make_float2(a, b));
  return *reinterpret_cast<unsigned int*>(&h);
}
static __device__ __forceinline__ int mask_at(const void* mt, int fmt, int idx) {
  if (fmt == 0) return ((const int*)mt)[idx] != 0;
  if (fmt == 1) return ((const unsigned char*)mt)[idx] != 0;
  if (fmt == 2) return ((const float*)mt)[idx] != 0.0f;
  return ((const unsigned short*)mt)[idx] != 0;
}
static __device__ __forceinline__ int pos_at(const int* pos, int i64, size_t idx) {
  return i64 ? pos[idx * 2] : pos[idx];
}
static __device__ __forceinline__ void gload16(const void* g, void* l) {
  __builtin_amdgcn_global_load_lds((const __attribute__((address_space(1))) void*)g,
                                   (__attribute__((address_space(3))) void*)l,
                                   16, 0, 0);
}

// ---------- mega-fused prologue: pack_mask | weight transpose | LN ----------
// blocks [0,512):    pack_mask (T*T/32 = 131072 words / 256 = 512 blocks)
// blocks [512,768):  64x64 LDS tile weight transpose (Wqkv then Wproj)
// blocks [768,4864): LayerNorm, 4 rows/block (one row per wave), inline affine fold
__global__ __launch_bounds__(256) void prologue_kernel(
    const int* __restrict__ pos, const void* __restrict__ mt,
    unsigned int* __restrict__ mp,
    const float* __restrict__ Wq, const float* __restrict__ Wp,
    short* __restrict__ WqT, short* __restrict__ WpT,
    const float* __restrict__ x,
    const float* __restrict__ lnw, const float* __restrict__ lnb,
    const float* __restrict__ afw, const float* __restrict__ afb,
    short* __restrict__ xp)
{
  __shared__ float lds[64][65];
  const int bid0 = blockIdx.x;
  const int t = threadIdx.x;

  if (bid0 < 512) {            // ---- phase A: pack_mask ----
    __shared__ int s01, sf, sbf, szero;
    if (t == 0) { s01 = 1; sf = 1; sbf = 1; szero = 0; }
    __syncthreads();
    {
      const unsigned int* mtw = (const unsigned int*)mt;
      const unsigned int* posw = (const unsigned int*)pos;
      int a01 = 1, af = 1, ab = 1, zc = 0;
      for (int i = t; i < 1023; i += 256) {
        const unsigned int v = mtw[i];
        if (v > 1u) a01 = 0;
        const float f = __uint_as_float(v);
        if (!(f == 0.0f || f == 1.0f)) af = 0;
        const unsigned int lo = v & 0xFFFFu, hi = v >> 16;
        if (!((lo == 0u || lo == 0x3F80u) && (hi == 0u || hi == 0x3F80u))) ab = 0;
      }
      for (int i = t; i < 512; i += 256) if (posw[2 * i + 1] == 0u) zc++;
      if (!a01) atomicAnd(&s01, 0);
      if (!af)  atomicAnd(&sf, 0);
      if (!ab)  atomicAnd(&sbf, 0);
      if (zc)   atomicAdd(&szero, zc);
      __syncthreads();
    }
    const int fmt = s01 ? 0 : (sf ? 2 : (sbf ? 3 : 1));
    const int i64 = (szero > 500) ? 1 : 0;
    const int idx = bid0 * 256 + t;              // [0, 131072)
    const int q = idx >> 6;                      // [0, 2048)
    const int wrd = idx & 63;
    const size_t base = (size_t)q * T_SEQ + wrd * 32;
    unsigned int bits = 0;
    #pragma unroll 4
    for (int j = 0; j < 32; ++j)
      bits |= (mask_at(mt, fmt, pos_at(pos, i64, base + j)) ? 1u : 0u) << j;
    mp[idx] = bits;
    return;
  }

  if (bid0 < 768) {            // ---- phase B: weight transpose (256 blocks) ----
    int bid = bid0 - 512;
    const float* W; short* Wt; int N, n0, k0;
    if (bid < 192) { W = Wq; Wt = WqT; N = 1536; n0 = (bid % 24) * 64; k0 = (bid / 24) * 64; }
    else { bid -= 192; W = Wp; Wt = WpT; N = 512; n0 = (bid & 7) * 64; k0 = (bid >> 3) * 64; }
    const int tc = t & 63, tr = t >> 6;
    #pragma unroll
    for (int i = 0; i < 16; ++i) {
      const int kl = tr * 16 + i;
      lds[kl][tc] = W[(size_t)(k0 + kl) * N + n0 + tc];
    }
    __syncthreads();
    #pragma unroll
    for (int i = 0; i < 16; ++i) {
      const int nl = tr * 16 + i;
      Wt[(size_t)(n0 + nl) * 512 + k0 + tc] = f2bs(lds[tc][nl]);
    }
    return;
  }

  // ---- phase C: LayerNorm, 4 rows/block (one row per 64-lane wave) ----
  const int row = (bid0 - 768) * 4 + (t >> 6);   // [0, 16384)
  const int tid = t & 63;
  const float4* p = (const float4*)(x + (size_t)row * NEMBD + tid * 8);
  const float4 a0 = p[0], a1 = p[1];
  float f[8] = {a0.x, a0.y, a0.z, a0.w, a1.x, a1.y, a1.z, a1.w};
  float s = 0.f, s2 = 0.f;
  #pragma unroll
  for (int j = 0; j < 8; ++j) { s += f[j]; s2 += f[j] * f[j]; }
  #pragma unroll
  for (int off = 1; off < 64; off <<= 1) {
    s  += __shfl_xor(s, off);
    s2 += __shfl_xor(s2, off);
  }
  const float mean = s * (1.0f / NEMBD);
  const float rstd = rsqrtf(s2 * (1.0f / NEMBD) - mean * mean + 1e-5f);
  const float4* w1p = (const float4*)(lnw + tid * 8);
  const float4* b1p = (const float4*)(lnb + tid * 8);
  const float4* w2p = (const float4*)(afw + tid * 8);
  const float4* b2p = (const float4*)(afb + tid * 8);
  short8 ob;
  #pragma unroll
  for (int half = 0; half < 2; ++half) {
    const float4 W1 = w1p[half], B1 = b1p[half], W2 = w2p[half], B2 = b2p[half];
    const float* fb = f + half * 4;
    ob[half * 4 + 0] = f2bs(((fb[0] - mean) * rstd * W1.x + B1.x) * W2.x + B2.x);
    ob[half * 4 + 1] = f2bs(((fb[1] - mean) * rstd * W1.y + B1.y) * W2.y + B2.y);
    ob[half * 4 + 2] = f2bs(((fb[2] - mean) * rstd * W1.z + B1.z) * W2.z + B2.z);
    ob[half * 4 + 3] = f2bs(((fb[3] - mean) * rstd * W1.w + B1.w) * W2.w + B2.w);
  }
  *((short8*)(xp + (size_t)row * NEMBD + tid * 8)) = ob;
}

// ---------- GEMM (round-18 body) + T1 XCD-grouped block swizzle ----------
// 1D grid; each XCD owns a contiguous m-range: A-slice 2MB + B panel <=1.5MB
// fit its 4MB L2 (A reuse across n-tiles becomes L2-local).
// MODE 0: NB=12 (N=1536), scatter -> Q(scaled), K [bh][t][d], V^T [bh][d][t]
// MODE 1: NB=4 (N=512), fp32 out
template<int MODE>
__global__ __launch_bounds__(256) void gemm_kernel(
    const short* __restrict__ A, const short* __restrict__ Bt,
    void* __restrict__ out0, short* __restrict__ Kp, short* __restrict__ Vt)
{
  constexpr int NB = (MODE == 0) ? 12 : 4;
  constexpr int PER = (128 * NB) / 8;    // blocks per XCD group
  __shared__ alignas(16) short Atile[128 * 64];
  __shared__ alignas(16) short Btile[128 * 64];
  const int tid = threadIdx.x;
  const int l = tid & 63;
  const int w = tid >> 6;
  const int swz = (blockIdx.x & 7) * PER + (blockIdx.x >> 3);
  const int m0 = (swz / NB) * 128;
  const int n0 = (swz % NB) * 128;
  const int w_r = w >> 1, w_c = w & 1;
  const int lr = l & 15, lg = l >> 4;
  const int key = lr & 7;
  f32x4 acc[4][4] = {};

  for (int kt = 0; kt < 512; kt += 64) {
    #pragma unroll
    for (int i = 0; i < 4; ++i) {
      const int c = i * 256 + tid;
      const int row = c >> 3, col8 = c & 7;
      gload16(A  + (size_t)(m0 + row) * 512 + kt + (col8 ^ (row & 7)) * 8,
              Atile + (i * 256 + w * 64) * 8);
      gload16(Bt + (size_t)(n0 + row) * 512 + kt + (col8 ^ (row & 7)) * 8,
              Btile + (i * 256 + w * 64) * 8);
    }
    __syncthreads();
    #pragma unroll
    for (int kk = 0; kk < 2; ++kk) {
      short8 af[4], bfm[4];
      #pragma unroll
      for (int m = 0; m < 4; ++m)
        af[m] = *(const short8*)((char*)Atile
            + (w_r * 64 + m * 16 + lr) * 128 + ((kk * 4 + lg) ^ key) * 16);
      #pragma unroll
      for (int n = 0; n < 4; ++n)
        bfm[n] = *(const short8*)((char*)Btile
            + (w_c * 64 + n * 16 + lr) * 128 + ((kk * 4 + lg) ^ key) * 16);
      #pragma unroll
      for (int m = 0; m < 4; ++m)
        #pragma unroll
        for (int n = 0; n < 4; ++n)
          acc[m][n] = __builtin_amdgcn_mfma_f32_16x16x32_bf16(af[m], bfm[n], acc[m][n], 0, 0, 0);
    }
    __syncthreads();
  }

  if (MODE == 1) {
    float* out = (float*)out0;
    #pragma unroll
    for (int m = 0; m < 4; ++m)
      #pragma unroll
      for (int n = 0; n < 4; ++n)
        #pragma unroll
        for (int r = 0; r < 4; ++r) {
          const int gm = m0 + w_r * 64 + m * 16 + lg * 4 + r;
          const int gn = n0 + w_c * 64 + n * 16 + lr;
          out[(size_t)gm * NEMBD + gn] = acc[m][n][r];
        }
  } else {
    const int which = n0 >> 9;
    const int h = (n0 >> 7) & 3;
    short* Qp = (short*)out0;
    #pragma unroll
    for (int m = 0; m < 4; ++m)
      #pragma unroll
      for (int n = 0; n < 4; ++n)
        #pragma unroll
        for (int r = 0; r < 4; ++r) {
          const int gm = m0 + w_r * 64 + m * 16 + lg * 4 + r;
          const int b = gm >> 11, t = gm & 2047;
          const int d = w_c * 64 + n * 16 + lr;
          const size_t bh = (size_t)((b << 2) | h);
          const float v = acc[m][n][r];
          if (which == 0)      Qp[(bh * T_SEQ + t) * HDIM + d] = f2bs(v * QSCALE);
          else if (which == 1) Kp[(bh * T_SEQ + t) * HDIM + d] = f2bs(v);
          else                 Vt[(bh * HDIM + d) * T_SEQ + t] = f2bs(v);
        }
  }
}

// ---------- flash attention v9 (round-18 version, verbatim): Pw round-trip + b128 PV ----------
// Journal rule: PV B-operands must be single b128 reads; dual-b64 pi-mapped reads
// regressed twice (rounds 11, 19: conflicts 11.5M -> 25.2M).
__global__ __launch_bounds__(512, 4) void attn_kernel(
    const short* __restrict__ Q, const short* __restrict__ Kp, const short* __restrict__ Vt,
    const unsigned int* __restrict__ maskP, short* __restrict__ O)
{
  __shared__ alignas(16) short Kt[3][32 * 128];   // 3 x 8 KB, chunk ^= row&7
  __shared__ alignas(16) short Vs[3][128 * 32];   // 3 x 8 KB, chunk ^= (row>>1)&3
  __shared__ alignas(16) short Pw[8][16 * 40];    // 10 KB (stride 40: 2-way pattern)
  const int tid = threadIdx.x;
  const int l = tid & 63;
  const int w = tid >> 6;                          // 0..7
  const int lr = l & 15, lg = l >> 4;
  const int s7 = lr & 7;
  const int vkey = (lr >> 1) & 3;
  const int swz = ((blockIdx.x & 7) << 6) | (blockIdx.x >> 3);
  const int bh = swz >> 4;
  const int q0 = (swz & 15) * 128 + w * 16;
  const short* Qb = Q  + (size_t)bh * T_SEQ * HDIM;
  const short* Kb = Kp + (size_t)bh * T_SEQ * HDIM;
  const short* Vb = Vt + (size_t)bh * HDIM * T_SEQ;

  const int kr = tid >> 4, kc = tid & 15;
  const int vr = tid >> 2, vc = tid & 3;
  #define STAGE(b, kti) do {                                                        \
    const int kt_ = (kti) * 32;                                                     \
    gload16(Kb + (size_t)(kt_ + kr) * HDIM + (kc ^ (kr & 7)) * 8,                   \
            (char*)&Kt[b][0] + w * 1024);                                           \
    gload16(Vb + (size_t)vr * T_SEQ + kt_ + (vc ^ ((vr >> 1) & 3)) * 8,             \
            (char*)&Vs[b][0] + w * 1024);                                           \
  } while (0)

  short8 aq[4];
  #pragma unroll
  for (int kk = 0; kk < 4; ++kk)
    aq[kk] = *(const short8*)(Qb + (size_t)(q0 + lr) * HDIM + kk * 32 + lg * 8);

  float lsum = 0.f;
  f32x4 acc[8] = {};
  const size_t mrow = (size_t)(q0 + lr) * 64;

  STAGE(0, 0);
  int bc = 0, bn = 1;
  for (int kti = 0; kti < 64; ++kti) {
    if (kti + 1 < 64) {
      STAGE(bn, kti + 1);
      asm volatile("s_waitcnt vmcnt(2)" ::: "memory");
    } else {
      asm volatile("s_waitcnt vmcnt(0)" ::: "memory");
    }
    __builtin_amdgcn_sched_barrier(0);
    __builtin_amdgcn_s_barrier();
    const unsigned int mq = maskP[mrow + kti];
    f32x4 sn[2];
    __builtin_amdgcn_s_setprio(1);
    #pragma unroll
    for (int n = 0; n < 2; ++n) {
      f32x4 s = {};
      #pragma unroll
      for (int kk = 0; kk < 4; ++kk) {
        const short8 bk = *(const short8*)((char*)&Kt[bc][0]
            + (n * 16 + lr) * 256 + ((kk * 4 + lg) ^ s7) * 16);
        s = __builtin_amdgcn_mfma_f32_16x16x32_bf16(bk, aq[kk], s, 0, 0, 0);
      }
      sn[n] = s;
    }
    __builtin_amdgcn_s_setprio(0);
    #pragma unroll
    for (int n = 0; n < 2; ++n) {
      const int base = n * 16 + lg * 4;
      const float p0 = __builtin_amdgcn_exp2f(((mq >> (base + 0)) & 1) ? sn[n][0] : -1e9f);
      const float p1 = __builtin_amdgcn_exp2f(((mq >> (base + 1)) & 1) ? sn[n][1] : -1e9f);
      const float p2 = __builtin_amdgcn_exp2f(((mq >> (base + 2)) & 1) ? sn[n][2] : -1e9f);
      const float p3 = __builtin_amdgcn_exp2f(((mq >> (base + 3)) & 1) ? sn[n][3] : -1e9f);
      lsum += (p0 + p1) + (p2 + p3);
      union { short4v s4; unsigned int u[2]; } pwv;
      pwv.u[0] = pk2(p0, p1);
      pwv.u[1] = pk2(p2, p3);
      *(short4v*)&Pw[w][lr * 40 + base] = pwv.s4;
    }
    const short8 pa = *(const short8*)&Pw[w][lr * 40 + lg * 8];
    __builtin_amdgcn_s_setprio(1);
    #pragma unroll
    for (int nn = 0; nn < 8; ++nn) {
      const short8 bv = *(const short8*)((char*)&Vs[bc][0]
          + (nn * 16 + lr) * 64 + (lg ^ vkey) * 16);
      acc[nn] = __builtin_amdgcn_mfma_f32_16x16x32_bf16(pa, bv, acc[nn], 0, 0, 0);
    }
    __builtin_amdgcn_s_setprio(0);
    bc = bn;
    bn = (bn == 2) ? 0 : bn + 1;
  }
  #undef STAGE

  float s = lsum;
  s += __shfl_xor(s, 16);
  s += __shfl_xor(s, 32);
  const float rin = 1.0f / s;
  float rin4[4];
  #pragma unroll
  for (int r = 0; r < 4; ++r) rin4[r] = __shfl(rin, lg * 4 + r);
  const int b = bh >> 2, h = bh & 3;
  #pragma unroll
  for (int nn = 0; nn < 8; ++nn) {
    const int d = nn * 16 + lr;
    #pragma unroll
    for (int r = 0; r < 4; ++r) {
      const int qg = q0 + lg * 4 + r;
      O[((size_t)b * T_SEQ + qg) * NEMBD + h * HDIM + d] = f2bs(acc[nn][r] * rin4[r]);
    }
  }
}

// workspace-too-small sentinel (should never fire; ws proven >= 103 MB)
__global__ __launch_bounds__(256) void fill_kernel(float* __restrict__ out, float v, size_t n) {
  for (size_t i = blockIdx.x * 256 + threadIdx.x; i < n; i += (size_t)gridDim.x * 256)
    out[i] = v;
}

extern "C" void kernel_launch(void* const* d_in, const int* in_sizes, int n_in,
                              void* d_out, int out_size, void* d_ws, size_t ws_size,
                              hipStream_t stream)
{
  const float* x     = (const float*)d_in[0];
  const int*   pos   = (const int*)d_in[1];
  const float* lnw   = (const float*)d_in[2];
  const float* lnb   = (const float*)d_in[3];
  const float* afw   = (const float*)d_in[4];
  const float* afb   = (const float*)d_in[5];
  const float* Wqkv  = (const float*)d_in[6];
  const void*  mtab  = d_in[7];
  const float* Wproj = (const float*)d_in[8];

  size_t off = 0;
  char* ws = (char*)d_ws;
  unsigned int* maskP = (unsigned int*)(ws + off); off += (size_t)T_SEQ * 64 * 4;
  short* Xp  = (short*)(ws + off);                 off += (size_t)MROWS * NEMBD * 2;
  short* WqT = (short*)(ws + off);                 off += (size_t)3 * NEMBD * NEMBD * 2;
  short* WpT = (short*)(ws + off);                 off += (size_t)NEMBD * NEMBD * 2;
  short* Qb  = (short*)(ws + off);                 off += (size_t)BATCH * NHEAD * T_SEQ * HDIM * 2;
  short* Kb  = (short*)(ws + off);                 off += (size_t)BATCH * NHEAD * T_SEQ * HDIM * 2;
  short* Vt  = (short*)(ws + off);                 off += (size_t)BATCH * NHEAD * T_SEQ * HDIM * 2;
  short* Ob  = Xp;   // Xp dead after gemm<0>

  if (ws_size < off) {
    fill_kernel<<<256, 256, 0, stream>>>((float*)d_out, (float)(ws_size >> 20), (size_t)out_size);
    return;
  }

  prologue_kernel<<<4864, 256, 0, stream>>>(pos, mtab, maskP, Wqkv, Wproj, WqT, WpT,
                                            x, lnw, lnb, afw, afb, Xp);
  gemm_kernel<0><<<1536, 256, 0, stream>>>(Xp, WqT, (void*)Qb, Kb, Vt);
  attn_kernel<<<512, 512, 0, stream>>>(Qb, Kb, Vt, maskP, Ob);
  gemm_kernel<1><<<512, 256, 0, stream>>>(Ob, WpT, d_out, nullptr, nullptr);
}

// Round 24
// 199.091 us; speedup vs baseline: 1.0462x; 1.0462x over previous
//
#include <hip/hip_runtime.h>
#include <hip/hip_bf16.h>

#define T_SEQ 2048
#define NEMBD 512
#define NHEAD 4
#define HDIM  128
#define BATCH 8
#define MROWS (BATCH * T_SEQ)          // 16384
// 1/sqrt(128) * log2(e): QK^T scores land in log2 domain -> exp2 in softmax
#define QSCALE 0.12751744534f

typedef __attribute__((ext_vector_type(8))) short short8;
typedef __attribute__((ext_vector_type(4))) short short4v;
typedef __attribute__((ext_vector_type(4))) float f32x4;

static __device__ __forceinline__ float bf2f(unsigned short h) {
  return __uint_as_float(((unsigned int)h) << 16);
}
static __device__ __forceinline__ short f2bs(float f) {   // RNE f32->bf16 bits
  unsigned int u = __float_as_uint(f);
  unsigned int r = (u + 0x7FFFu + ((u >> 16) & 1u)) >> 16;
  return (short)r;
}
// pack two floats -> u32 of 2 bf16 (v_cvt_pk_bf16_f32)
static __device__ __forceinline__ unsigned int pk2(float a, float b) {
  __hip_bfloat162 h = __float22bfloat162_rn(make_float2(a, b));
  return *reinterpret_cast<unsigned int*>(&h);
}
static __device__ __forceinline__ int mask_at(const void* mt, int fmt, int idx) {
  if (fmt == 0) return ((const int*)mt)[idx] != 0;
  if (fmt == 1) return ((const unsigned char*)mt)[idx] != 0;
  if (fmt == 2) return ((const float*)mt)[idx] != 0.0f;
  return ((const unsigned short*)mt)[idx] != 0;
}
static __device__ __forceinline__ int pos_at(const int* pos, int i64, size_t idx) {
  return i64 ? pos[idx * 2] : pos[idx];
}
static __device__ __forceinline__ void gload16(const void* g, void* l) {
  __builtin_amdgcn_global_load_lds((const __attribute__((address_space(1))) void*)g,
                                   (__attribute__((address_space(3))) void*)l,
                                   16, 0, 0);
}

// ---------- mega-fused prologue: pack_mask | weight transpose | LN ----------
// blocks [0,512):    pack_mask (T*T/32 = 131072 words / 256 = 512 blocks)
// blocks [512,768):  64x64 LDS tile weight transpose (Wqkv then Wproj)
// blocks [768,4864): LayerNorm, 4 rows/block (one row per wave), inline affine fold
__global__ __launch_bounds__(256) void prologue_kernel(
    const int* __restrict__ pos, const void* __restrict__ mt,
    unsigned int* __restrict__ mp,
    const float* __restrict__ Wq, const float* __restrict__ Wp,
    short* __restrict__ WqT, short* __restrict__ WpT,
    const float* __restrict__ x,
    const float* __restrict__ lnw, const float* __restrict__ lnb,
    const float* __restrict__ afw, const float* __restrict__ afb,
    short* __restrict__ xp)
{
  __shared__ float lds[64][65];
  const int bid0 = blockIdx.x;
  const int t = threadIdx.x;

  if (bid0 < 512) {            // ---- phase A: pack_mask ----
    __shared__ int s01, sf, sbf, szero;
    if (t == 0) { s01 = 1; sf = 1; sbf = 1; szero = 0; }
    __syncthreads();
    {
      const unsigned int* mtw = (const unsigned int*)mt;
      const unsigned int* posw = (const unsigned int*)pos;
      int a01 = 1, af = 1, ab = 1, zc = 0;
      for (int i = t; i < 1023; i += 256) {
        const unsigned int v = mtw[i];
        if (v > 1u) a01 = 0;
        const float f = __uint_as_float(v);
        if (!(f == 0.0f || f == 1.0f)) af = 0;
        const unsigned int lo = v & 0xFFFFu, hi = v >> 16;
        if (!((lo == 0u || lo == 0x3F80u) && (hi == 0u || hi == 0x3F80u))) ab = 0;
      }
      for (int i = t; i < 512; i += 256) if (posw[2 * i + 1] == 0u) zc++;
      if (!a01) atomicAnd(&s01, 0);
      if (!af)  atomicAnd(&sf, 0);
      if (!ab)  atomicAnd(&sbf, 0);
      if (zc)   atomicAdd(&szero, zc);
      __syncthreads();
    }
    const int fmt = s01 ? 0 : (sf ? 2 : (sbf ? 3 : 1));
    const int i64 = (szero > 500) ? 1 : 0;
    const int idx = bid0 * 256 + t;              // [0, 131072)
    const int q = idx >> 6;                      // [0, 2048)
    const int wrd = idx & 63;
    const size_t base = (size_t)q * T_SEQ + wrd * 32;
    unsigned int bits = 0;
    #pragma unroll 4
    for (int j = 0; j < 32; ++j)
      bits |= (mask_at(mt, fmt, pos_at(pos, i64, base + j)) ? 1u : 0u) << j;
    mp[idx] = bits;
    return;
  }

  if (bid0 < 768) {            // ---- phase B: weight transpose (256 blocks) ----
    int bid = bid0 - 512;
    const float* W; short* Wt; int N, n0, k0;
    if (bid < 192) { W = Wq; Wt = WqT; N = 1536; n0 = (bid % 24) * 64; k0 = (bid / 24) * 64; }
    else { bid -= 192; W = Wp; Wt = WpT; N = 512; n0 = (bid & 7) * 64; k0 = (bid >> 3) * 64; }
    const int tc = t & 63, tr = t >> 6;
    #pragma unroll
    for (int i = 0; i < 16; ++i) {
      const int kl = tr * 16 + i;
      lds[kl][tc] = W[(size_t)(k0 + kl) * N + n0 + tc];
    }
    __syncthreads();
    #pragma unroll
    for (int i = 0; i < 16; ++i) {
      const int nl = tr * 16 + i;
      Wt[(size_t)(n0 + nl) * 512 + k0 + tc] = f2bs(lds[tc][nl]);
    }
    return;
  }

  // ---- phase C: LayerNorm, 4 rows/block (one row per 64-lane wave) ----
  const int row = (bid0 - 768) * 4 + (t >> 6);   // [0, 16384)
  const int tid = t & 63;
  const float4* p = (const float4*)(x + (size_t)row * NEMBD + tid * 8);
  const float4 a0 = p[0], a1 = p[1];
  float f[8] = {a0.x, a0.y, a0.z, a0.w, a1.x, a1.y, a1.z, a1.w};
  float s = 0.f, s2 = 0.f;
  #pragma unroll
  for (int j = 0; j < 8; ++j) { s += f[j]; s2 += f[j] * f[j]; }
  #pragma unroll
  for (int off = 1; off < 64; off <<= 1) {
    s  += __shfl_xor(s, off);
    s2 += __shfl_xor(s2, off);
  }
  const float mean = s * (1.0f / NEMBD);
  const float rstd = rsqrtf(s2 * (1.0f / NEMBD) - mean * mean + 1e-5f);
  const float4* w1p = (const float4*)(lnw + tid * 8);
  const float4* b1p = (const float4*)(lnb + tid * 8);
  const float4* w2p = (const float4*)(afw + tid * 8);
  const float4* b2p = (const float4*)(afb + tid * 8);
  short8 ob;
  #pragma unroll
  for (int half = 0; half < 2; ++half) {
    const float4 W1 = w1p[half], B1 = b1p[half], W2 = w2p[half], B2 = b2p[half];
    const float* fb = f + half * 4;
    ob[half * 4 + 0] = f2bs(((fb[0] - mean) * rstd * W1.x + B1.x) * W2.x + B2.x);
    ob[half * 4 + 1] = f2bs(((fb[1] - mean) * rstd * W1.y + B1.y) * W2.y + B2.y);
    ob[half * 4 + 2] = f2bs(((fb[2] - mean) * rstd * W1.z + B1.z) * W2.z + B2.z);
    ob[half * 4 + 3] = f2bs(((fb[3] - mean) * rstd * W1.w + B1.w) * W2.w + B2.w);
  }
  *((short8*)(xp + (size_t)row * NEMBD + tid * 8)) = ob;
}

// ---------- GEMM (round-18/22 version): BK=64 + both-sides XOR swizzle, 2D grid ----------
template<int MODE>
__global__ __launch_bounds__(256) void gemm_kernel(
    const short* __restrict__ A, const short* __restrict__ Bt,
    void* __restrict__ out0, short* __restrict__ Kp, short* __restrict__ Vt)
{
  __shared__ alignas(16) short Atile[128 * 64];
  __shared__ alignas(16) short Btile[128 * 64];
  const int tid = threadIdx.x;
  const int l = tid & 63;
  const int w = tid >> 6;
  const int m0 = blockIdx.x * 128;
  const int n0 = blockIdx.y * 128;
  const int w_r = w >> 1, w_c = w & 1;
  const int lr = l & 15, lg = l >> 4;
  const int key = lr & 7;
  f32x4 acc[4][4] = {};

  for (int kt = 0; kt < 512; kt += 64) {
    #pragma unroll
    for (int i = 0; i < 4; ++i) {
      const int c = i * 256 + tid;
      const int row = c >> 3, col8 = c & 7;
      gload16(A  + (size_t)(m0 + row) * 512 + kt + (col8 ^ (row & 7)) * 8,
              Atile + (i * 256 + w * 64) * 8);
      gload16(Bt + (size_t)(n0 + row) * 512 + kt + (col8 ^ (row & 7)) * 8,
              Btile + (i * 256 + w * 64) * 8);
    }
    __syncthreads();
    #pragma unroll
    for (int kk = 0; kk < 2; ++kk) {
      short8 af[4], bfm[4];
      #pragma unroll
      for (int m = 0; m < 4; ++m)
        af[m] = *(const short8*)((char*)Atile
            + (w_r * 64 + m * 16 + lr) * 128 + ((kk * 4 + lg) ^ key) * 16);
      #pragma unroll
      for (int n = 0; n < 4; ++n)
        bfm[n] = *(const short8*)((char*)Btile
            + (w_c * 64 + n * 16 + lr) * 128 + ((kk * 4 + lg) ^ key) * 16);
      #pragma unroll
      for (int m = 0; m < 4; ++m)
        #pragma unroll
        for (int n = 0; n < 4; ++n)
          acc[m][n] = __builtin_amdgcn_mfma_f32_16x16x32_bf16(af[m], bfm[n], acc[m][n], 0, 0, 0);
    }
    __syncthreads();
  }

  if (MODE == 1) {
    float* out = (float*)out0;
    #pragma unroll
    for (int m = 0; m < 4; ++m)
      #pragma unroll
      for (int n = 0; n < 4; ++n)
        #pragma unroll
        for (int r = 0; r < 4; ++r) {
          const int gm = m0 + w_r * 64 + m * 16 + lg * 4 + r;
          const int gn = n0 + w_c * 64 + n * 16 + lr;
          out[(size_t)gm * NEMBD + gn] = acc[m][n][r];
        }
  } else {
    const int which = n0 >> 9;
    const int h = (n0 >> 7) & 3;
    short* Qp = (short*)out0;
    #pragma unroll
    for (int m = 0; m < 4; ++m)
      #pragma unroll
      for (int n = 0; n < 4; ++n)
        #pragma unroll
        for (int r = 0; r < 4; ++r) {
          const int gm = m0 + w_r * 64 + m * 16 + lg * 4 + r;
          const int b = gm >> 11, t = gm & 2047;
          const int d = w_c * 64 + n * 16 + lr;
          const size_t bh = (size_t)((b << 2) | h);
          const float v = acc[m][n][r];
          if (which == 0)      Qp[(bh * T_SEQ + t) * HDIM + d] = f2bs(v * QSCALE);
          else if (which == 1) Kp[(bh * T_SEQ + t) * HDIM + d] = f2bs(v);
          else                 Vt[(bh * HDIM + d) * T_SEQ + t] = f2bs(v);
        }
  }
}

// ---------- flash attention v9 (final): 3-ring counted-vmcnt, swapped QK^T,
// lane-local log2 softmax, Pw round-trip + single-b128 PV (dual-b64 regressed 2x) ----------
__global__ __launch_bounds__(512, 4) void attn_kernel(
    const short* __restrict__ Q, const short* __restrict__ Kp, const short* __restrict__ Vt,
    const unsigned int* __restrict__ maskP, short* __restrict__ O)
{
  __shared__ alignas(16) short Kt[3][32 * 128];   // 3 x 8 KB, chunk ^= row&7
  __shared__ alignas(16) short Vs[3][128 * 32];   // 3 x 8 KB, chunk ^= (row>>1)&3
  __shared__ alignas(16) short Pw[8][16 * 40];    // 10 KB (stride 40: 2-way pattern)
  const int tid = threadIdx.x;
  const int l = tid & 63;
  const int w = tid >> 6;                          // 0..7
  const int lr = l & 15, lg = l >> 4;
  const int s7 = lr & 7;
  const int vkey = (lr >> 1) & 3;
  const int swz = ((blockIdx.x & 7) << 6) | (blockIdx.x >> 3);
  const int bh = swz >> 4;
  const int q0 = (swz & 15) * 128 + w * 16;
  const short* Qb = Q  + (size_t)bh * T_SEQ * HDIM;
  const short* Kb = Kp + (size_t)bh * T_SEQ * HDIM;
  const short* Vb = Vt + (size_t)bh * HDIM * T_SEQ;

  const int kr = tid >> 4, kc = tid & 15;
  const int vr = tid >> 2, vc = tid & 3;
  #define STAGE(b, kti) do {                                                        \
    const int kt_ = (kti) * 32;                                                     \
    gload16(Kb + (size_t)(kt_ + kr) * HDIM + (kc ^ (kr & 7)) * 8,                   \
            (char*)&Kt[b][0] + w * 1024);                                           \
    gload16(Vb + (size_t)vr * T_SEQ + kt_ + (vc ^ ((vr >> 1) & 3)) * 8,             \
            (char*)&Vs[b][0] + w * 1024);                                           \
  } while (0)

  short8 aq[4];
  #pragma unroll
  for (int kk = 0; kk < 4; ++kk)
    aq[kk] = *(const short8*)(Qb + (size_t)(q0 + lr) * HDIM + kk * 32 + lg * 8);

  float lsum = 0.f;
  f32x4 acc[8] = {};
  const size_t mrow = (size_t)(q0 + lr) * 64;

  STAGE(0, 0);
  int bc = 0, bn = 1;
  for (int kti = 0; kti < 64; ++kti) {
    if (kti + 1 < 64) {
      STAGE(bn, kti + 1);
      asm volatile("s_waitcnt vmcnt(2)" ::: "memory");
    } else {
      asm volatile("s_waitcnt vmcnt(0)" ::: "memory");
    }
    __builtin_amdgcn_sched_barrier(0);
    __builtin_amdgcn_s_barrier();
    const unsigned int mq = maskP[mrow + kti];
    f32x4 sn[2];
    __builtin_amdgcn_s_setprio(1);
    #pragma unroll
    for (int n = 0; n < 2; ++n) {
      f32x4 s = {};
      #pragma unroll
      for (int kk = 0; kk < 4; ++kk) {
        const short8 bk = *(const short8*)((char*)&Kt[bc][0]
            + (n * 16 + lr) * 256 + ((kk * 4 + lg) ^ s7) * 16);
        s = __builtin_amdgcn_mfma_f32_16x16x32_bf16(bk, aq[kk], s, 0, 0, 0);
      }
      sn[n] = s;
    }
    __builtin_amdgcn_s_setprio(0);
    #pragma unroll
    for (int n = 0; n < 2; ++n) {
      const int base = n * 16 + lg * 4;
      const float p0 = __builtin_amdgcn_exp2f(((mq >> (base + 0)) & 1) ? sn[n][0] : -1e9f);
      const float p1 = __builtin_amdgcn_exp2f(((mq >> (base + 1)) & 1) ? sn[n][1] : -1e9f);
      const float p2 = __builtin_amdgcn_exp2f(((mq >> (base + 2)) & 1) ? sn[n][2] : -1e9f);
      const float p3 = __builtin_amdgcn_exp2f(((mq >> (base + 3)) & 1) ? sn[n][3] : -1e9f);
      lsum += (p0 + p1) + (p2 + p3);
      union { short4v s4; unsigned int u[2]; } pwv;
      pwv.u[0] = pk2(p0, p1);
      pwv.u[1] = pk2(p2, p3);
      *(short4v*)&Pw[w][lr * 40 + base] = pwv.s4;
    }
    const short8 pa = *(const short8*)&Pw[w][lr * 40 + lg * 8];
    __builtin_amdgcn_s_setprio(1);
    #pragma unroll
    for (int nn = 0; nn < 8; ++nn) {
      const short8 bv = *(const short8*)((char*)&Vs[bc][0]
          + (nn * 16 + lr) * 64 + (lg ^ vkey) * 16);
      acc[nn] = __builtin_amdgcn_mfma_f32_16x16x32_bf16(pa, bv, acc[nn], 0, 0, 0);
    }
    __builtin_amdgcn_s_setprio(0);
    bc = bn;
    bn = (bn == 2) ? 0 : bn + 1;
  }
  #undef STAGE

  float s = lsum;
  s += __shfl_xor(s, 16);
  s += __shfl_xor(s, 32);
  const float rin = 1.0f / s;
  float rin4[4];
  #pragma unroll
  for (int r = 0; r < 4; ++r) rin4[r] = __shfl(rin, lg * 4 + r);
  const int b = bh >> 2, h = bh & 3;
  #pragma unroll
  for (int nn = 0; nn < 8; ++nn) {
    const int d = nn * 16 + lr;
    #pragma unroll
    for (int r = 0; r < 4; ++r) {
      const int qg = q0 + lg * 4 + r;
      O[((size_t)b * T_SEQ + qg) * NEMBD + h * HDIM + d] = f2bs(acc[nn][r] * rin4[r]);
    }
  }
}

// workspace-too-small sentinel (should never fire; ws proven >= 103 MB)
__global__ __launch_bounds__(256) void fill_kernel(float* __restrict__ out, float v, size_t n) {
  for (size_t i = blockIdx.x * 256 + threadIdx.x; i < n; i += (size_t)gridDim.x * 256)
    out[i] = v;
}

extern "C" void kernel_launch(void* const* d_in, const int* in_sizes, int n_in,
                              void* d_out, int out_size, void* d_ws, size_t ws_size,
                              hipStream_t stream)
{
  const float* x     = (const float*)d_in[0];
  const int*   pos   = (const int*)d_in[1];
  const float* lnw   = (const float*)d_in[2];
  const float* lnb   = (const float*)d_in[3];
  const float* afw   = (const float*)d_in[4];
  const float* afb   = (const float*)d_in[5];
  const float* Wqkv  = (const float*)d_in[6];
  const void*  mtab  = d_in[7];
  const float* Wproj = (const float*)d_in[8];

  size_t off = 0;
  char* ws = (char*)d_ws;
  unsigned int* maskP = (unsigned int*)(ws + off); off += (size_t)T_SEQ * 64 * 4;
  short* Xp  = (short*)(ws + off);                 off += (size_t)MROWS * NEMBD * 2;
  short* WqT = (short*)(ws + off);                 off += (size_t)3 * NEMBD * NEMBD * 2;
  short* WpT = (short*)(ws + off);                 off += (size_t)NEMBD * NEMBD * 2;
  short* Qb  = (short*)(ws + off);                 off += (size_t)BATCH * NHEAD * T_SEQ * HDIM * 2;
  short* Kb  = (short*)(ws + off);                 off += (size_t)BATCH * NHEAD * T_SEQ * HDIM * 2;
  short* Vt  = (short*)(ws + off);                 off += (size_t)BATCH * NHEAD * T_SEQ * HDIM * 2;
  short* Ob  = Xp;   // Xp dead after gemm<0>

  if (ws_size < off) {
    fill_kernel<<<256, 256, 0, stream>>>((float*)d_out, (float)(ws_size >> 20), (size_t)out_size);
    return;
  }

  prologue_kernel<<<4864, 256, 0, stream>>>(pos, mtab, maskP, Wqkv, Wproj, WqT, WpT,
                                            x, lnw, lnb, afw, afb, Xp);
  dim3 g0(128, 12);
  gemm_kernel<0><<<g0, 256, 0, stream>>>(Xp, WqT, (void*)Qb, Kb, Vt);
  attn_kernel<<<512, 512, 0, stream>>>(Qb, Kb, Vt, maskP, Ob);
  dim3 g1(128, 4);
  gemm_kernel<1><<<g1, 256, 0, stream>>>(Ob, WpT, d_out, nullptr, nullptr);
}